// Round 8
// baseline (849.677 us; speedup 1.0000x reference)
//
#include <hip/hip_runtime.h>
#include <math.h>

// C=48, DM=24, DIN=48, DS=8, DC=4, DTR=2, B=2, D=H=W=32, L=32768
#define LL   32768
#define NCH  1024          // scan chunks per sequence
#define LC   32            // chunk length
#define BL48 3145728       // B*48*L floats == 2*48*LL
// OB row: [g][pos][112] bf16 = dt(0..47)|xc(48..95)|B(96..103)|C(104..111)
#define OBW 112
#define OBROW(g,pos) (((size_t)(g)*LL + (pos))*OBW)
#define ZROW(g,pos)  (((size_t)(g)*LL + (pos))*48)

typedef unsigned short ushort_t;
typedef ushort_t ushort8 __attribute__((ext_vector_type(8)));
typedef ushort_t ushort4v __attribute__((ext_vector_type(4)));

__device__ __forceinline__ float sigmoidf_(float x){ return 1.0f/(1.0f+__expf(-x)); }
__device__ __forceinline__ float softplusf_(float x){ return (x > 20.0f) ? x : log1pf(__expf(x)); }
__device__ __forceinline__ ushort_t f2bf(float f){
  union { float f; unsigned u; } v; v.f = f;
  unsigned r = v.u + 0x7FFFu + ((v.u >> 16) & 1u);
  return (ushort_t)(r >> 16);
}
__device__ __forceinline__ float bf2f(ushort_t h){
  union { unsigned u; float f; } v; v.u = ((unsigned)h) << 16;
  return v.f;
}

// ---------------------------------------------------------------------------
// Fused LN + in-proj + conv + silu + x-proj + dt + in-LDS scan phase 1.
// tile = 64 positions, block = 192, one (b,dir) per blockIdx.{y,z}.
// Phase 1 (t<140): r=t>>1, half=t&1: LN + in-proj half (x->LDS, z->LDS).
// Phase 2 (t<128): p=t>>1, half=t&1 (24 d-ch each): conv+silu+xc, x-proj
//   partials pair-reduced via shfl_xor(1), dt, B/C -> LDS row stage.
// Coop write: 64 contiguous 224B rows (OB) + 96B rows (Z), fully coalesced.
// Phase 3 (192 thr = 2 chunks x 48 d x 2 s-halves): chunk scan -> PS fp32.
// ---------------------------------------------------------------------------
extern "C" __global__ void __launch_bounds__(192)
k_inconv(const float* __restrict__ cur,
         const float* __restrict__ lng, const float* __restrict__ lnb,
         const float* __restrict__ in_w, const float* __restrict__ conv_w,
         const float* __restrict__ conv_b, const float* __restrict__ xproj_w,
         const float* __restrict__ dt_w, const float* __restrict__ dt_b,
         const float* __restrict__ A_log,
         ushort_t* __restrict__ OB, ushort_t* __restrict__ Z,
         float* __restrict__ PS, int orient)
{
  __shared__ ushort_t xz[70][56];      // pre-conv x rows bf16 (3+64+3 halo)  7.84 KB
  __shared__ ushort_t srow[64][112];   // dt|xc|B|C per position             14.0 KB
  __shared__ ushort_t sz[64][48];      // raw z per position                  6.0 KB
  const int t   = threadIdx.x;
  const int b   = blockIdx.y;
  const int dir = blockIdx.z;
  const int bs  = blockIdx.x * 64;
  const int j   = 2*orient + dir;
  const int g   = 2*dir + b;
  const int ch0 = dir*24;
  const float* iw = in_w + j*2304;   // (96,24)

  // ---- phase 1: LN + in-proj ----
  if (t < 140){
    const int r = t >> 1, half = t & 1;
    const int l = bs - 3 + r;
    float u[24];
    if (l >= 0 && l < LL) {
      const float* p = cur + (size_t)b*48*LL + l;
      float v[48]; float mu = 0.f;
      #pragma unroll
      for (int c2 = 0; c2 < 48; c2++){ v[c2] = p[(size_t)c2*LL]; mu += v[c2]; }
      mu *= (1.f/48.f);
      float var = 0.f;
      #pragma unroll
      for (int c2 = 0; c2 < 48; c2++){ float dd = v[c2]-mu; var += dd*dd; }
      float rstd = rsqrtf(var*(1.f/48.f) + 1e-5f);
      #pragma unroll
      for (int c2 = 0; c2 < 24; c2++)
        u[c2] = (v[ch0+c2]-mu)*rstd*lng[ch0+c2] + lnb[ch0+c2];
    } else {
      #pragma unroll
      for (int c2 = 0; c2 < 24; c2++) u[c2]=0.f;
    }
    if (half == 0){
      // x-half (e 0..47) -> LDS
      for (int e0 = 0; e0 < 48; e0 += 8){
        ushort8 o;
        #pragma unroll
        for (int k = 0; k < 8; k++){
          float s = 0.f;
          #pragma unroll
          for (int d = 0; d < 24; d++) s += u[d]*iw[(e0+k)*24+d];
          o[k] = f2bf(s);
        }
        *(ushort8*)(&xz[r][e0]) = o;
      }
    } else if (r >= 3 && r < 67){
      // z-half (e 48..95) -> LDS z stage (own rows only)
      for (int e0 = 48; e0 < 96; e0 += 8){
        ushort8 o;
        #pragma unroll
        for (int k = 0; k < 8; k++){
          float s = 0.f;
          #pragma unroll
          for (int d = 0; d < 24; d++) s += u[d]*iw[(e0+k)*24+d];
          o[k] = f2bf(s);
        }
        *(ushort8*)(&sz[r-3][e0-48]) = o;
      }
    }
  }
  __syncthreads();

  // ---- phase 2: conv + silu + xc + x-proj + dt + B/C -> LDS row stage ----
  if (t < 128){
    const int p    = t >> 1;
    const int half = t & 1;          // d channels half*24 .. +23
    const int d0   = half*24;
    const float* cw = conv_w + j*192;   // (48,4)
    const float* cb = conv_b + j*48;
    const float* xw = xproj_w + j*864;  // (18,48)
    float xd[18];
    #pragma unroll
    for (int q = 0; q < 18; q++) xd[q]=0.f;
    #pragma unroll
    for (int dd0 = 0; dd0 < 24; dd0 += 8){
      ushort8 a[4];
      #pragma unroll
      for (int rr = 0; rr < 4; rr++){
        int row = dir ? (p+6-rr) : (p+rr);   // row for conv tap kk=rr
        a[rr] = *(const ushort8*)(&xz[row][d0+dd0]);
      }
      ushort8 oxc;
      #pragma unroll
      for (int k = 0; k < 8; k++){
        int d = d0 + dd0 + k;
        float acc = cb[d];
        #pragma unroll
        for (int kk = 0; kk < 4; kk++)
          acc += bf2f(a[kk][k]) * cw[d*4+kk];
        acc = acc * sigmoidf_(acc);   // silu
        oxc[k] = f2bf(acc);
        #pragma unroll
        for (int q = 0; q < 18; q++) xd[q] += acc*xw[q*48+d];
      }
      *(ushort8*)(&srow[p][48+d0+dd0]) = oxc;
    }
    // pair-reduce xd across the two halves (adjacent lanes)
    #pragma unroll
    for (int q = 0; q < 18; q++) xd[q] += __shfl_xor(xd[q], 1);

    // dt for own 24 channels
    const float* dw = dt_w + j*96;  // (48,2)
    const float* db = dt_b + j*48;
    #pragma unroll
    for (int q8 = 0; q8 < 24; q8 += 8){
      ushort8 o;
      #pragma unroll
      for (int k = 0; k < 8; k++){
        int d = d0 + q8 + k;
        o[k] = f2bf(softplusf_(xd[0]*dw[d*2] + xd[1]*dw[d*2+1] + db[d]));
      }
      *(ushort8*)(&srow[p][d0+q8]) = o;
    }
    // B/C: half0 -> B (xd[2..9]), half1 -> C (xd[10..17])
    ushort8 o;
    #pragma unroll
    for (int k = 0; k < 8; k++) o[k] = f2bf(xd[2+half*8+k]);
    *(ushort8*)(&srow[p][96+half*8]) = o;
  }
  __syncthreads();

  // ---- cooperative coalesced writes (latency hides under phase 3) ----
  {
    const int G0 = dir ? (LL-64-bs) : bs;
    ushort_t* ob = OB + OBROW(g, G0);
    #pragma unroll
    for (int idx = t; idx < 1792; idx += 192){   // 64 rows x 28 ushort4
      int q = idx/28, w = (idx%28)*4;
      int lr = dir ? (63-q) : q;
      *(ushort4v*)(ob + (size_t)q*OBW + w) = *(const ushort4v*)(&srow[lr][w]);
    }
    ushort_t* zp = Z + ZROW(g, G0);
    #pragma unroll
    for (int idx = t; idx < 768; idx += 192){    // 64 rows x 12 ushort4
      int q = idx/12, w = (idx%12)*4;
      int lr = dir ? (63-q) : q;
      *(ushort4v*)(zp + (size_t)q*48 + w) = *(const ushort4v*)(&sz[lr][w]);
    }
  }

  // ---- phase 3: fused scan1 (2 chunks x 48 d x 2 s-halves) ----
  {
    const int ck = t/96, r = t%96, d = r%48, sh = (r/48)*4;
    const int c = dir ? ((LL-64-bs)/32 + ck) : (bs/32 + ck);
    const float* Al = A_log + j*384 + d*8 + sh;
    float A[4];
    #pragma unroll
    for (int k = 0; k < 4; k++) A[k] = -__expf(Al[k]);
    float P[4] = {1.f,1.f,1.f,1.f}, S[4] = {0.f,0.f,0.f,0.f};
    #pragma unroll 4
    for (int j2 = 0; j2 < 32; j2++){
      int pp = dir ? (63 - ck*32 - j2) : (ck*32 + j2);
      float dtv = bf2f(srow[pp][d]);
      float xv  = bf2f(srow[pp][48+d]);
      ushort4v bv = *(const ushort4v*)(&srow[pp][96+sh]);
      float dx = dtv*xv;
      #pragma unroll
      for (int k = 0; k < 4; k++){
        float dA = __expf(dtv*A[k]);
        P[k] *= dA;
        S[k] = S[k]*dA + dx*bf2f(bv[k]);
      }
    }
    float* out = PS + ((size_t)g*NCH + c)*768 + d*8 + sh;
    *(float4*)(out)     = make_float4(P[0],P[1],P[2],P[3]);
    *(float4*)(out+384) = make_float4(S[0],S[1],S[2],S[3]);
  }
}

// ---------------------------------------------------------------------------
// Scan phase 2, parallel: 64-lane segment per (g,st) chain; lane owns 16
// chunks; Kogge-Stone affine scan across lanes; replay writes h-at-start.
// ---------------------------------------------------------------------------
extern "C" __global__ void __launch_bounds__(256)
k_scan2(float* __restrict__ PS)
{
  const int t = blockIdx.x*256 + threadIdx.x;
  const int chain = t >> 6;          // 0..1535
  const int lane  = t & 63;
  const int g  = chain / 384;
  const int st = chain % 384;
  float* base = PS + (size_t)g*NCH*768 + st;
  float P[16], S[16];
  const int c0 = lane*16;
  #pragma unroll
  for (int k = 0; k < 16; k++){
    P[k] = base[(size_t)(c0+k)*768];
    S[k] = base[(size_t)(c0+k)*768 + 384];
  }
  float Pl = 1.f, Sl = 0.f;
  #pragma unroll
  for (int k = 0; k < 16; k++){ Sl = P[k]*Sl + S[k]; Pl = P[k]*Pl; }
  float Pi = Pl, Si = Sl;
  #pragma unroll
  for (int off = 1; off < 64; off <<= 1){
    float Pp = __shfl_up(Pi, off);
    float Sp = __shfl_up(Si, off);
    if (lane >= off){ Si = Pi*Sp + Si; Pi = Pi*Pp; }
  }
  float h = __shfl_up(Si, 1);
  if (lane == 0) h = 0.f;
  #pragma unroll
  for (int k = 0; k < 16; k++){
    base[(size_t)(c0+k)*768 + 384] = h;
    h = fmaf(P[k], h, S[k]);
  }
}

// ---------------------------------------------------------------------------
// Scan phase 3 + gate + out-proj + residual. ONE direction per block
// (blockIdx.z): fwd writes channels 0..23, bwd writes 24..47 (disjoint).
// Block = 192 = 4 groups x 48 lanes; group pr scans chunk c (pos space),
// covering output l in [bx*128 + pr*32, +32) for both dirs.
// ---------------------------------------------------------------------------
extern "C" __global__ void __launch_bounds__(192)
k_scan3c(const ushort_t* __restrict__ OB, const ushort_t* __restrict__ Z,
         const float* __restrict__ A_log, const float* __restrict__ Dp,
         const float* __restrict__ PS, const float* __restrict__ out_w,
         const float* __restrict__ resid, float* __restrict__ outp, int orient)
{
  __shared__ ushort_t yt[4][32][50];
  const int t = threadIdx.x;
  const int d  = t % 48;
  const int pr = t / 48;
  const int b  = blockIdx.y;
  const int dir = blockIdx.z;
  const int bx = blockIdx.x;
  const int g = 2*dir + b;
  const int j = 2*orient + dir;
  const int cf = bx*4 + pr;
  const int c  = dir ? (NCH-1-cf) : cf;

  {
    const float* Al = A_log + j*384 + d*8;
    const float* hp = PS + ((size_t)g*NCH + c)*768 + 384 + d*8;
    float A[8], h[8];
    float4 h0 = *(const float4*)(hp);
    float4 h1 = *(const float4*)(hp+4);
    h[0]=h0.x; h[1]=h0.y; h[2]=h0.z; h[3]=h0.w;
    h[4]=h1.x; h[5]=h1.y; h[6]=h1.z; h[7]=h1.w;
    #pragma unroll
    for (int s = 0; s < 8; s++) A[s] = -__expf(Al[s]);
    const float Dpd = Dp[j*48 + d];
    const ushort_t* rw = OB + OBROW(g, c*LC);
    const ushort_t* zw = Z + ZROW(g, c*LC);
    for (int j2 = 0; j2 < LC; j2++){
      const ushort_t* row = rw + (size_t)j2*OBW;
      float dtv = bf2f(row[d]);
      float xcv = bf2f(row[48+d]);
      float zv  = bf2f(zw[(size_t)j2*48 + d]);
      ushort8 br = *(const ushort8*)(row + 96);
      ushort8 cr = *(const ushort8*)(row + 104);
      float dx = dtv*xcv;
      float y = 0.f;
      #pragma unroll
      for (int s = 0; s < 8; s++){
        float dA = __expf(dtv*A[s]);
        h[s] = h[s]*dA + dx*bf2f(br[s]);
        y += h[s]*bf2f(cr[s]);
      }
      y += xcv*Dpd;
      int sl = dir ? (31-j2) : j2;
      yt[pr][sl][d] = f2bf(y * (zv * sigmoidf_(zv)));
    }
  }
  __syncthreads();

  // ---- out-proj (own dir's 24 channels) + residual, planar write ----
  if (t < 128){
    const int sub = t >> 5, pp = t & 31;
    const int l = bx*128 + sub*32 + pp;
    const float* ow = out_w + (size_t)j*1152;    // (24,48)
    float o[24];
    #pragma unroll
    for (int e = 0; e < 24; e++) o[e]=0.f;
    for (int dd = 0; dd < 48; dd++){
      float vv = bf2f(yt[sub][pp][dd]);
      #pragma unroll
      for (int e = 0; e < 24; e++) o[e] += vv*ow[e*48+dd];
    }
    const size_t pb = (size_t)b*48*LL + (size_t)(dir*24)*LL + l;
    #pragma unroll
    for (int e = 0; e < 24; e++){
      outp[pb + (size_t)e*LL] = o[e] + resid[pb + (size_t)e*LL];
    }
  }
}

// ---------------------------------------------------------------------------
// Digit-rotation transpose: out[t] = in[(t%32)*1024 + (t/32)] per plane,
// optionally + x.
// ---------------------------------------------------------------------------
extern "C" __global__ void __launch_bounds__(256)
k_perm(const float* __restrict__ in, const float* __restrict__ xadd,
       float* __restrict__ out, int addx)
{
  __shared__ float t[32][33];
  const int q = blockIdx.y;            // plane: b*48 + c
  const float* ip = in + (size_t)q*LL;
  float* op = out + (size_t)q*LL;
  const int ab0 = blockIdx.x*32;
  const int tx = threadIdx.x & 31, ty = threadIdx.x >> 5;
  #pragma unroll
  for (int k = 0; k < 4; k++){
    int c = ty + 8*k;
    t[c][tx] = ip[(size_t)c*1024 + ab0 + tx];
  }
  __syncthreads();
  #pragma unroll
  for (int k = 0; k < 4; k++){
    int ab = ty + 8*k;
    float v = t[tx][ab];
    size_t o = (size_t)(ab0+ab)*32 + tx;
    if (addx) v += xadd[(size_t)q*LL + o];
    op[o] = v;
  }
}

extern "C" void kernel_launch(void* const* d_in, const int* in_sizes, int n_in,
                              void* d_out, int out_size, void* d_ws, size_t ws_size,
                              hipStream_t stream)
{
  const float* x       = (const float*)d_in[0];
  const float* ln_g    = (const float*)d_in[1];
  const float* ln_b    = (const float*)d_in[2];
  const float* in_w    = (const float*)d_in[3];
  const float* conv_w  = (const float*)d_in[4];
  const float* conv_b  = (const float*)d_in[5];
  const float* xproj_w = (const float*)d_in[6];
  const float* dt_w    = (const float*)d_in[7];
  const float* dt_b    = (const float*)d_in[8];
  const float* A_log   = (const float*)d_in[9];
  const float* Dp      = (const float*)d_in[10];
  const float* out_w   = (const float*)d_in[11];
  float* out = (float*)d_out;

  char* w = (char*)d_ws;
  ushort_t* OB   = (ushort_t*)w;  w += (size_t)4*LL*OBW*2;   // 29.4 MB
  ushort_t* Z    = (ushort_t*)w;  w += (size_t)4*LL*48*2;    // 12.6 MB
  float*    PS   = (float*)w;     w += (size_t)4*NCH*768*4;  // 12.6 MB
  float*    sout = (float*)w;     w += (size_t)BL48*4;       // 12.6 MB
  float*    curT = (float*)w;     w += (size_t)BL48*4;       // 12.6 MB

  for (int i = 0; i < 3; i++){
    const float* ip;
    if (i == 0) ip = x;
    else {
      k_perm<<<dim3(32, 96), 256, 0, stream>>>(sout, x, curT, 0);
      ip = curT;
    }
    k_inconv<<<dim3(LL/64, 2, 2), 192, 0, stream>>>(ip, ln_g + i*48, ln_b + i*48,
        in_w, conv_w, conv_b, xproj_w, dt_w, dt_b, A_log, OB, Z, PS, i);
    k_scan2<<<dim3(384), 256, 0, stream>>>(PS);
    k_scan3c<<<dim3(NCH/4, 2, 2), 192, 0, stream>>>(OB, Z, A_log, Dp, PS,
        out_w, ip, sout, i);
  }
  k_perm<<<dim3(32, 96), 256, 0, stream>>>(sout, x, out, 1);
}

// Round 9
// 588.714 us; speedup vs baseline: 1.4433x; 1.4433x over previous
//
#include <hip/hip_runtime.h>
#include <math.h>

// C=48, DM=24, DIN=48, DS=8, DC=4, DTR=2, B=2, D=H=W=32, L=32768
#define LL   32768
#define NCH  1024          // scan chunks per sequence
#define LC   32            // chunk length
#define BL48 3145728       // B*48*L floats == 2*48*LL
#define ROW48(g,l) (((size_t)(g)*LL + (l))*48)
#define ROW16(g,l) (((size_t)(g)*LL + (l))*16)

typedef unsigned short ushort_t;
typedef ushort_t ushort8 __attribute__((ext_vector_type(8)));

__device__ __forceinline__ float sigmoidf_(float x){ return 1.0f/(1.0f+__expf(-x)); }
__device__ __forceinline__ float softplusf_(float x){ return (x > 20.0f) ? x : log1pf(__expf(x)); }
__device__ __forceinline__ ushort_t f2bf(float f){
  union { float f; unsigned u; } v; v.f = f;
  unsigned r = v.u + 0x7FFFu + ((v.u >> 16) & 1u);
  return (ushort_t)(r >> 16);
}
__device__ __forceinline__ float bf2f(ushort_t h){
  union { unsigned u; float f; } v; v.u = ((unsigned)h) << 16;
  return v.f;
}

// ---------------------------------------------------------------------------
// Flat fused LN + in-proj + conv(silu) + x-proj + dt + z: ONE THREAD PER
// POSITION, no LDS, no syncthreads. Conv halo via 3 wave-shuffles per channel
// (shfl_up for fwd, shfl_down for bwd). Waves overlap by 3 lanes: wave w
// covers l = 61*w - 3 + lane; fwd stores lanes 3..63, bwd stores lanes 0..60.
// Outputs bf16 rows: dtb/xcb/zb [g][pos][48], BCB [g][pos][16]; g = 2*dir+b;
// backward stored at flipped pos.
// ---------------------------------------------------------------------------
extern "C" __global__ void __launch_bounds__(64)
k_flat(const float* __restrict__ cur,
       const float* __restrict__ lng, const float* __restrict__ lnb,
       const float* __restrict__ in_w, const float* __restrict__ conv_w,
       const float* __restrict__ conv_b, const float* __restrict__ xproj_w,
       const float* __restrict__ dt_w, const float* __restrict__ dt_b,
       ushort_t* __restrict__ dtb, ushort_t* __restrict__ xcb,
       ushort_t* __restrict__ zb, ushort_t* __restrict__ BCB, int orient)
{
  const int lane = threadIdx.x;
  const int wid  = blockIdx.x;
  const int b    = blockIdx.y;
  const int dir  = blockIdx.z;
  const int j    = 2*orient + dir;
  const int g    = 2*dir + b;
  const int ch0  = dir*24;
  const int l    = wid*61 - 3 + lane;
  const bool inr = (l >= 0 && l < LL);
  const bool own = inr && (dir ? (lane <= 60) : (lane >= 3));

  // ---- LN ----
  float u[24];
  if (inr){
    const float* p = cur + (size_t)b*48*LL + l;
    float v[48]; float mu = 0.f;
    #pragma unroll
    for (int c2 = 0; c2 < 48; c2++){ v[c2] = p[(size_t)c2*LL]; mu += v[c2]; }
    mu *= (1.f/48.f);
    float var = 0.f;
    #pragma unroll
    for (int c2 = 0; c2 < 48; c2++){ float dd = v[c2]-mu; var += dd*dd; }
    float rstd = rsqrtf(var*(1.f/48.f) + 1e-5f);
    #pragma unroll
    for (int c2 = 0; c2 < 24; c2++)
      u[c2] = (v[ch0+c2]-mu)*rstd*lng[ch0+c2] + lnb[ch0+c2];
  } else {
    #pragma unroll
    for (int c2 = 0; c2 < 24; c2++) u[c2] = 0.f;
  }

  const float* iw = in_w + j*2304;    // (96,24)
  const float* cw = conv_w + j*192;   // (48,4)
  const float* cb = conv_b + j*48;
  const float* xw = xproj_w + j*864;  // (18,48)
  const int pos = dir ? (LL-1-l) : l;
  ushort_t* xcr = xcb + ROW48(g, pos);

  // ---- x-half in-proj + conv(shfl) + silu + x-proj partials ----
  float xd[18];
  #pragma unroll
  for (int q = 0; q < 18; q++) xd[q] = 0.f;
  #pragma unroll
  for (int d0 = 0; d0 < 48; d0 += 8){
    ushort8 oxc;
    #pragma unroll
    for (int k = 0; k < 8; k++){
      const int d = d0 + k;
      float xzv = 0.f;
      #pragma unroll
      for (int c2 = 0; c2 < 24; c2++) xzv += u[c2]*iw[d*24+c2];
      float t1, t2, t3;
      if (dir){ t1 = __shfl_down(xzv,1); t2 = __shfl_down(xzv,2); t3 = __shfl_down(xzv,3); }
      else    { t1 = __shfl_up(xzv,1);   t2 = __shfl_up(xzv,2);   t3 = __shfl_up(xzv,3); }
      float acc = cb[d] + cw[d*4+3]*xzv + cw[d*4+2]*t1 + cw[d*4+1]*t2 + cw[d*4+0]*t3;
      acc = acc * sigmoidf_(acc);   // silu
      oxc[k] = f2bf(acc);
      #pragma unroll
      for (int q = 0; q < 18; q++) xd[q] += acc*xw[q*48+d];
    }
    if (own) *(ushort8*)(xcr + d0) = oxc;
  }

  // ---- dt ----
  const float* dw = dt_w + j*96;   // (48,2)
  const float* db = dt_b + j*48;
  ushort_t* dtr = dtb + ROW48(g, pos);
  #pragma unroll
  for (int d0 = 0; d0 < 48; d0 += 8){
    ushort8 o;
    #pragma unroll
    for (int k = 0; k < 8; k++){
      const int d = d0 + k;
      o[k] = f2bf(softplusf_(xd[0]*dw[d*2] + xd[1]*dw[d*2+1] + db[d]));
    }
    if (own) *(ushort8*)(dtr + d0) = o;
  }

  // ---- B/C ----
  if (own){
    ushort_t* bc = BCB + ROW16(g, pos);
    ushort8 ob, oc;
    #pragma unroll
    for (int k = 0; k < 8; k++){ ob[k] = f2bf(xd[2+k]); oc[k] = f2bf(xd[10+k]); }
    *(ushort8*)(bc)   = ob;
    *(ushort8*)(bc+8) = oc;
  }

  // ---- z-half in-proj ----
  ushort_t* zr = zb + ROW48(g, pos);
  #pragma unroll
  for (int e0 = 48; e0 < 96; e0 += 8){
    ushort8 o;
    #pragma unroll
    for (int k = 0; k < 8; k++){
      float s = 0.f;
      #pragma unroll
      for (int c2 = 0; c2 < 24; c2++) s += u[c2]*iw[(e0+k)*24+c2];
      o[k] = f2bf(s);
    }
    if (own) *(ushort8*)(zr + (e0-48)) = o;
  }
}

// ---------------------------------------------------------------------------
// Scan phase 1: lane = d (48 per stream), 4 streams per block (block=192).
// Per (g, chunk): P[s]=prod dA, S[s]=local scan from 0. PS layout [g][c][768]
// fp32: P at [d*8+s], S at [384+d*8+s].
// ---------------------------------------------------------------------------
extern "C" __global__ void __launch_bounds__(192)
k_scan1(const ushort_t* __restrict__ dtb, const ushort_t* __restrict__ xcb,
        const ushort_t* __restrict__ BCB, const float* __restrict__ A_log,
        float* __restrict__ PS, int orient)
{
  const int d = threadIdx.x % 48;
  const int sid = blockIdx.x*4 + threadIdx.x/48;
  const int c = sid & (NCH-1);
  const int g = sid >> 10;          // dir*2 + b
  const int dir = g >> 1;
  const float* Al = A_log + (2*orient+dir)*384 + d*8;
  float A[8], P[8], S[8];
  #pragma unroll
  for (int s = 0; s < 8; s++){ A[s] = -__expf(Al[s]); P[s]=1.f; S[s]=0.f; }
  const ushort_t* pdt = dtb + ROW48(g, c*LC) + d;
  const ushort_t* pxc = xcb + ROW48(g, c*LC) + d;
  const ushort_t* pbc = BCB + ROW16(g, c*LC);
  #pragma unroll 4
  for (int j = 0; j < LC; j++){
    float dtv = bf2f(pdt[(size_t)j*48]);
    float xcv = bf2f(pxc[(size_t)j*48]);
    ushort8 br = *(const ushort8*)(pbc + (size_t)j*16);
    float dx = dtv*xcv;
    #pragma unroll
    for (int s = 0; s < 8; s++){
      float dA = __expf(dtv*A[s]);
      P[s] *= dA;
      S[s] = S[s]*dA + dx*bf2f(br[s]);
    }
  }
  float* out = PS + ((size_t)g*NCH + c)*768 + d*8;
  *(float4*)(out)       = make_float4(P[0],P[1],P[2],P[3]);
  *(float4*)(out+4)     = make_float4(P[4],P[5],P[6],P[7]);
  *(float4*)(out+384)   = make_float4(S[0],S[1],S[2],S[3]);
  *(float4*)(out+388)   = make_float4(S[4],S[5],S[6],S[7]);
}

// ---------------------------------------------------------------------------
// Scan phase 2, parallel: 64-lane segment per (g,st) chain; lane owns 16
// chunks; Kogge-Stone affine scan across lanes; replay writes h-at-start.
// ---------------------------------------------------------------------------
extern "C" __global__ void __launch_bounds__(256)
k_scan2(float* __restrict__ PS)
{
  const int t = blockIdx.x*256 + threadIdx.x;
  const int chain = t >> 6;          // 0..1535
  const int lane  = t & 63;
  const int g  = chain / 384;
  const int st = chain % 384;
  float* base = PS + (size_t)g*NCH*768 + st;
  float P[16], S[16];
  const int c0 = lane*16;
  #pragma unroll
  for (int k = 0; k < 16; k++){
    P[k] = base[(size_t)(c0+k)*768];
    S[k] = base[(size_t)(c0+k)*768 + 384];
  }
  float Pl = 1.f, Sl = 0.f;
  #pragma unroll
  for (int k = 0; k < 16; k++){ Sl = P[k]*Sl + S[k]; Pl = P[k]*Pl; }
  float Pi = Pl, Si = Sl;
  #pragma unroll
  for (int off = 1; off < 64; off <<= 1){
    float Pp = __shfl_up(Pi, off);
    float Sp = __shfl_up(Si, off);
    if (lane >= off){ Si = Pi*Sp + Si; Pi = Pi*Pp; }
  }
  float h = __shfl_up(Si, 1);
  if (lane == 0) h = 0.f;
  #pragma unroll
  for (int k = 0; k < 16; k++){
    base[(size_t)(c0+k)*768 + 384] = h;
    h = fmaf(P[k], h, S[k]);
  }
}

// ---------------------------------------------------------------------------
// Scan phase 3 + gate + out-proj + residual. ONE direction per block
// (blockIdx.z): fwd writes channels 0..23, bwd 24..47 (disjoint planes).
// Block = 192 = 4 groups x 48 lanes; group pr scans chunk c (pos space),
// covering output l in [bx*128 + pr*32, +32). y staged bf16 in LDS.
// ---------------------------------------------------------------------------
extern "C" __global__ void __launch_bounds__(192)
k_scan3c(const ushort_t* __restrict__ dtb, const ushort_t* __restrict__ xcb,
         const ushort_t* __restrict__ zb, const ushort_t* __restrict__ BCB,
         const float* __restrict__ A_log, const float* __restrict__ Dp,
         const float* __restrict__ PS, const float* __restrict__ out_w,
         const float* __restrict__ resid, float* __restrict__ outp, int orient)
{
  __shared__ ushort_t yt[4][32][50];
  const int t = threadIdx.x;
  const int d  = t % 48;
  const int pr = t / 48;
  const int b  = blockIdx.y;
  const int dir = blockIdx.z;
  const int bx = blockIdx.x;
  const int g = 2*dir + b;
  const int j = 2*orient + dir;
  const int cf = bx*4 + pr;
  const int c  = dir ? (NCH-1-cf) : cf;

  {
    const float* Al = A_log + j*384 + d*8;
    const float* hp = PS + ((size_t)g*NCH + c)*768 + 384 + d*8;
    float A[8], h[8];
    float4 h0 = *(const float4*)(hp);
    float4 h1 = *(const float4*)(hp+4);
    h[0]=h0.x; h[1]=h0.y; h[2]=h0.z; h[3]=h0.w;
    h[4]=h1.x; h[5]=h1.y; h[6]=h1.z; h[7]=h1.w;
    #pragma unroll
    for (int s = 0; s < 8; s++) A[s] = -__expf(Al[s]);
    const float Dpd = Dp[j*48 + d];
    const ushort_t* pdt = dtb + ROW48(g, c*LC) + d;
    const ushort_t* pxc = xcb + ROW48(g, c*LC) + d;
    const ushort_t* pz  = zb  + ROW48(g, c*LC) + d;
    const ushort_t* pbc = BCB + ROW16(g, c*LC);
    for (int j2 = 0; j2 < LC; j2++){
      float dtv = bf2f(pdt[(size_t)j2*48]);
      float xcv = bf2f(pxc[(size_t)j2*48]);
      float zv  = bf2f(pz [(size_t)j2*48]);
      ushort8 br = *(const ushort8*)(pbc + (size_t)j2*16);
      ushort8 cr = *(const ushort8*)(pbc + (size_t)j2*16 + 8);
      float dx = dtv*xcv;
      float y = 0.f;
      #pragma unroll
      for (int s = 0; s < 8; s++){
        float dA = __expf(dtv*A[s]);
        h[s] = h[s]*dA + dx*bf2f(br[s]);
        y += h[s]*bf2f(cr[s]);
      }
      y += xcv*Dpd;
      int sl = dir ? (31-j2) : j2;
      yt[pr][sl][d] = f2bf(y * (zv * sigmoidf_(zv)));
    }
  }
  __syncthreads();

  // ---- out-proj (own dir's 24 channels) + residual, planar write ----
  if (t < 128){
    const int sub = t >> 5, pp = t & 31;
    const int l = bx*128 + sub*32 + pp;
    const float* ow = out_w + (size_t)j*1152;    // (24,48)
    float o[24];
    #pragma unroll
    for (int e = 0; e < 24; e++) o[e]=0.f;
    for (int dd = 0; dd < 48; dd++){
      float vv = bf2f(yt[sub][pp][dd]);
      #pragma unroll
      for (int e = 0; e < 24; e++) o[e] += vv*ow[e*48+dd];
    }
    const size_t pb = (size_t)b*48*LL + (size_t)(dir*24)*LL + l;
    #pragma unroll
    for (int e = 0; e < 24; e++){
      outp[pb + (size_t)e*LL] = o[e] + resid[pb + (size_t)e*LL];
    }
  }
}

// ---------------------------------------------------------------------------
// Digit-rotation transpose: out[t] = in[(t%32)*1024 + (t/32)] per plane,
// optionally + x.
// ---------------------------------------------------------------------------
extern "C" __global__ void __launch_bounds__(256)
k_perm(const float* __restrict__ in, const float* __restrict__ xadd,
       float* __restrict__ out, int addx)
{
  __shared__ float t[32][33];
  const int q = blockIdx.y;            // plane: b*48 + c
  const float* ip = in + (size_t)q*LL;
  float* op = out + (size_t)q*LL;
  const int ab0 = blockIdx.x*32;
  const int tx = threadIdx.x & 31, ty = threadIdx.x >> 5;
  #pragma unroll
  for (int k = 0; k < 4; k++){
    int c = ty + 8*k;
    t[c][tx] = ip[(size_t)c*1024 + ab0 + tx];
  }
  __syncthreads();
  #pragma unroll
  for (int k = 0; k < 4; k++){
    int ab = ty + 8*k;
    float v = t[tx][ab];
    size_t o = (size_t)(ab0+ab)*32 + tx;
    if (addx) v += xadd[(size_t)q*LL + o];
    op[o] = v;
  }
}

extern "C" void kernel_launch(void* const* d_in, const int* in_sizes, int n_in,
                              void* d_out, int out_size, void* d_ws, size_t ws_size,
                              hipStream_t stream)
{
  const float* x       = (const float*)d_in[0];
  const float* ln_g    = (const float*)d_in[1];
  const float* ln_b    = (const float*)d_in[2];
  const float* in_w    = (const float*)d_in[3];
  const float* conv_w  = (const float*)d_in[4];
  const float* conv_b  = (const float*)d_in[5];
  const float* xproj_w = (const float*)d_in[6];
  const float* dt_w    = (const float*)d_in[7];
  const float* dt_b    = (const float*)d_in[8];
  const float* A_log   = (const float*)d_in[9];
  const float* Dp      = (const float*)d_in[10];
  const float* out_w   = (const float*)d_in[11];
  float* out = (float*)d_out;

  char* w = (char*)d_ws;
  ushort_t* dtb  = (ushort_t*)w;  w += (size_t)4*LL*48*2;    // 12.6 MB
  ushort_t* xcb  = (ushort_t*)w;  w += (size_t)4*LL*48*2;    // 12.6 MB
  ushort_t* zbuf = (ushort_t*)w;  w += (size_t)4*LL*48*2;    // 12.6 MB
  ushort_t* BCB  = (ushort_t*)w;  w += (size_t)4*LL*16*2;    //  4.2 MB
  float*    PS   = (float*)w;     w += (size_t)4*NCH*768*4;  // 12.6 MB
  float*    sout = (float*)w;     w += (size_t)BL48*4;       // 12.6 MB
  float*    curT = (float*)w;     w += (size_t)BL48*4;       // 12.6 MB

  for (int i = 0; i < 3; i++){
    const float* ip;
    if (i == 0) ip = x;
    else {
      k_perm<<<dim3(32, 96), 256, 0, stream>>>(sout, x, curT, 0);
      ip = curT;
    }
    k_flat<<<dim3(540, 2, 2), 64, 0, stream>>>(ip, ln_g + i*48, ln_b + i*48,
        in_w, conv_w, conv_b, xproj_w, dt_w, dt_b, dtb, xcb, zbuf, BCB, i);
    k_scan1<<<dim3(NCH), 192, 0, stream>>>(dtb, xcb, BCB, A_log, PS, i);
    k_scan2<<<dim3(384), 256, 0, stream>>>(PS);
    k_scan3c<<<dim3(NCH/4, 2, 2), 192, 0, stream>>>(dtb, xcb, zbuf, BCB,
        A_log, Dp, PS, out_w, ip, sout, i);
  }
  k_perm<<<dim3(32, 96), 256, 0, stream>>>(sout, x, out, 1);
}